// Round 1
// baseline (3619.780 us; speedup 1.0000x reference)
//
#include <hip/hip_runtime.h>
#include <cstdint>
#include <cstddef>

#define Bn 8
#define Tn 8192
#define BT (Bn*Tn)      // 65536 points
#define Hn 128
#define RRn 16384       // 128*128 bins per plane per batch

// ---------------- index computation ----------------
__global__ void k_idx(const float* __restrict__ p, int* __restrict__ idx) {
  int i = blockIdx.x*256 + threadIdx.x;
  if (i >= BT) return;
  float v0 = p[i*3+0], v1 = p[i*3+1], v2 = p[i*3+2];
  float v[3] = {v0, v1, v2};
  const int A0[3] = {0,0,1};
  const int A1[3] = {2,1,2};
#pragma unroll
  for (int pl = 0; pl < 3; ++pl) {
    float a = v[A0[pl]] / 1.001f + 0.5f;
    float b = v[A1[pl]] / 1.001f + 0.5f;
    a = fminf(fmaxf(a, 0.0f), 0.999f);
    b = fminf(fmaxf(b, 0.0f), 0.999f);
    int ga = (int)floorf(a * 128.0f);
    int gb = (int)floorf(b * 128.0f);
    idx[pl*BT + i] = ga + 128*gb;
  }
}

__global__ void k_count(const int* __restrict__ idx, float* __restrict__ cnt) {
  int g = blockIdx.x*256 + threadIdx.x;
  if (g >= 3*BT) return;
  int pl = g / BT, i = g % BT;
  int b = i / Tn;
  int bin = idx[g];
  atomicAdd(&cnt[(pl*Bn + b)*RRn + bin], 1.0f);
}

// ---------------- input projection ----------------
template<bool CORR>
__global__ void k_proj(const float* __restrict__ p, const float* __restrict__ p2,
                       const float* __restrict__ wp, const float* __restrict__ bp,
                       const float* __restrict__ wp2, const float* __restrict__ bp2,
                       float* __restrict__ outLo, float* __restrict__ outHi) {
  int t = blockIdx.x;       // point index
  int c = threadIdx.x;      // 0..255 output channel
  float a0 = p[t*3+0], a1 = p[t*3+1], a2 = p[t*3+2];
  float v = a0*wp[c] + a1*wp[256+c] + a2*wp[512+c] + bp[c];
  if (CORR) {
    float q0 = p2[t*3+0], q1 = p2[t*3+1], q2 = p2[t*3+2];
    v += q0*wp2[c] + q1*wp2[256+c] + q2*wp2[512+c] + bp2[c];
  }
  if (c < 128) outLo[(size_t)t*128 + c] = v;
  else         outHi[(size_t)t*128 + (c-128)] = v;
}

// ---------------- generic segmented GEMM ----------------
// out[m][n] = bias[n] + sum over segments s: (relu_s? relu(x_s) : x_s)[m][0:128] @ W_s[0:128][0:128]
// M = BT rows, N = 128. Tile: 128 rows/block, 256 threads, 8x8 per thread.
template<int NSEG>
__global__ __launch_bounds__(256) void k_gemm(
    const float* __restrict__ x0g, const float* __restrict__ w0g,
    const float* __restrict__ x1g, const float* __restrict__ w1g,
    const float* __restrict__ x2g, const float* __restrict__ w2g,
    int reluMask, const float* __restrict__ bias, float* __restrict__ out)
{
  __shared__ float xs[128*33];     // [row][kk] padded stride 33
  __shared__ float wsm[32*128];    // [kk][col]
  const int tid = threadIdx.x;
  const int mr = tid & 15;         // row-thread
  const int nr = tid >> 4;         // col-thread (0..15)
  const size_t row0 = (size_t)blockIdx.x * 128;

  float acc[8][8];
#pragma unroll
  for (int i = 0; i < 8; ++i)
#pragma unroll
    for (int j = 0; j < 8; ++j) acc[i][j] = 0.0f;

  const float* Xg[3] = {x0g, x1g, x2g};
  const float* Wg[3] = {w0g, w1g, w2g};

#pragma unroll
  for (int s = 0; s < NSEG; ++s) {
    const float* __restrict__ X = Xg[s];
    const float* __restrict__ W = Wg[s];
    const bool rel = (reluMask >> s) & 1;
#pragma unroll 1
    for (int ch = 0; ch < 4; ++ch) {   // K chunks of 32 (segment K = 128)
      const int k0 = ch * 32;
      __syncthreads();
      {
        // stage x chunk: 128 rows x 32 k
        const int k4 = tid & 7;
        const int rb = tid >> 3;
#pragma unroll
        for (int rr = 0; rr < 4; ++rr) {
          const int row = rb + rr*32;
          float4 v = *reinterpret_cast<const float4*>(X + (row0+row)*128 + k0 + k4*4);
          if (rel) {
            v.x = fmaxf(v.x, 0.0f); v.y = fmaxf(v.y, 0.0f);
            v.z = fmaxf(v.z, 0.0f); v.w = fmaxf(v.w, 0.0f);
          }
          float* d = &xs[row*33 + k4*4];
          d[0] = v.x; d[1] = v.y; d[2] = v.z; d[3] = v.w;
        }
        // stage w chunk: 32 k x 128 cols
        const int c4 = tid & 31;
        const int kb = tid >> 5;
#pragma unroll
        for (int rr = 0; rr < 4; ++rr) {
          const int k = kb + rr*8;
          float4 v = *reinterpret_cast<const float4*>(W + (size_t)(k0+k)*128 + c4*4);
          *reinterpret_cast<float4*>(&wsm[k*128 + c4*4]) = v;
        }
      }
      __syncthreads();
#pragma unroll 8
      for (int kk = 0; kk < 32; ++kk) {
        float a[8], b[8];
#pragma unroll
        for (int i = 0; i < 8; ++i) a[i] = xs[(mr + 16*i)*33 + kk];
#pragma unroll
        for (int j = 0; j < 8; ++j) b[j] = wsm[kk*128 + nr*8 + j];
#pragma unroll
        for (int i = 0; i < 8; ++i)
#pragma unroll
          for (int j = 0; j < 8; ++j)
            acc[i][j] += a[i] * b[j];
      }
    }
  }
#pragma unroll
  for (int i = 0; i < 8; ++i) {
    const size_t row = row0 + mr + 16*i;
#pragma unroll
    for (int j = 0; j < 8; ++j) {
      out[row*128 + nr*8 + j] = acc[i][j] + bias[nr*8 + j];
    }
  }
}

// ---------------- pooling ----------------
__device__ __forceinline__ void atomicMaxF(float* addr, float val) {
  unsigned int bits = __float_as_uint(val);
  if (!(bits >> 31)) atomicMax((int*)addr, (int)bits);           // +0.0 and positive
  else               atomicMin((unsigned int*)addr, bits);       // -0.0 and negative
}

// reset only touched bins to -inf (only touched bins are ever gathered)
__global__ void k_reset(const int* __restrict__ idx, float* __restrict__ bins) {
  int g = blockIdx.x*256 + threadIdx.x;   // 3*BT*32
  int c4 = g & 31;
  int r = g >> 5;
  if (r >= 3*BT) return;
  int pl = r / BT, i = r % BT;
  int b = i / Tn;
  int bin = idx[pl*BT + i];
  const float ninf = -__builtin_inff();
  float4 v = make_float4(ninf, ninf, ninf, ninf);
  *reinterpret_cast<float4*>(&bins[((size_t)(pl*Bn + b)*RRn + bin)*128 + c4*4]) = v;
}

__global__ void k_scatter(const int* __restrict__ idx, const float* __restrict__ net,
                          float* __restrict__ bins) {
  int g = blockIdx.x*256 + threadIdx.x;   // 3*BT*128
  int chn = g & 127;
  int r = g >> 7;
  if (r >= 3*BT) return;
  int pl = r / BT, i = r % BT;
  int b = i / Tn;
  int bin = idx[pl*BT + i];
  float v = net[(size_t)i*128 + chn];
  atomicMaxF(&bins[((size_t)(pl*Bn + b)*RRn + bin)*128 + chn], v);
}

__global__ void k_gather(const int* __restrict__ idx, const float* __restrict__ bins,
                         float* __restrict__ pooled) {
  int g = blockIdx.x*256 + threadIdx.x;   // BT*128
  int chn = g & 127;
  int i = g >> 7;
  if (i >= BT) return;
  int b = i / Tn;
  float s = 0.0f;
#pragma unroll
  for (int pl = 0; pl < 3; ++pl) {
    int bin = idx[pl*BT + i];
    float v = bins[((size_t)(pl*Bn + b)*RRn + bin)*128 + chn];
    if (!isinf(v)) s += v;
  }
  pooled[(size_t)i*128 + chn] = s;
}

// ---------------- scatter-mean output ----------------
__global__ void k_scatter_add(const int* __restrict__ idxp, const float* __restrict__ c,
                              float* __restrict__ sums) {
  int g = blockIdx.x*256 + threadIdx.x;   // BT*128
  int chn = g & 127;
  int i = g >> 7;
  if (i >= BT) return;
  int b = i >> 13;   // /Tn
  int bin = idxp[i];
  atomicAdd(&sums[((size_t)b*RRn + bin)*128 + chn], c[(size_t)i*128 + chn]);
}

__global__ void k_finalize(const float* __restrict__ sums, const float* __restrict__ cnt,
                           float* __restrict__ outp) {
  int g = blockIdx.x*256 + threadIdx.x;   // Bn*128*RRn
  int bin = g & (RRn - 1);
  int chn = (g >> 14) & 127;
  int b = g >> 21;
  if (b >= Bn) return;
  float s = sums[((size_t)b*RRn + bin)*128 + chn];
  float n = cnt[b*RRn + bin];
  outp[((size_t)b*128 + chn)*RRn + bin] = s / fmaxf(n, 1.0f);
}

// ---------------- host ----------------
extern "C" void kernel_launch(void* const* d_in, const int* in_sizes, int n_in,
                              void* d_out_v, int out_size, void* d_ws, size_t ws_size,
                              hipStream_t stream) {
  const float* p    = (const float*)d_in[0];
  const float* p2   = (const float*)d_in[1];
  const float* wp   = (const float*)d_in[2];
  const float* bp   = (const float*)d_in[3];
  const float* wp2  = (const float*)d_in[4];
  const float* bp2  = (const float*)d_in[5];
  const float* bw0  = (const float*)d_in[6];
  const float* bb0  = (const float*)d_in[7];
  const float* bw1  = (const float*)d_in[8];
  const float* bb1  = (const float*)d_in[9];
  const float* bws  = (const float*)d_in[10];
  const float* cw0  = (const float*)d_in[11];
  const float* cb0  = (const float*)d_in[12];
  const float* cw1  = (const float*)d_in[13];
  const float* cb1  = (const float*)d_in[14];
  const float* cws  = (const float*)d_in[15];
  const float* fcw  = (const float*)d_in[16];
  const float* fcb  = (const float*)d_in[17];
  const float* fccw = (const float*)d_in[18];
  const float* fccb = (const float*)d_in[19];
  float* out = (float*)d_out_v;

  size_t off = 0;
  auto alloc = [&](size_t bytes) -> char* {
    char* r = (char*)d_ws + off;
    off += (bytes + 255) & ~(size_t)255;
    return r;
  };
  int*   idx  = (int*)  alloc((size_t)3*BT*4);
  float* cnt  = (float*)alloc((size_t)3*Bn*RRn*4);
  float* bufC = (float*)alloc((size_t)BT*128*4);  // tmp (hidden)  | sums lo
  float* bufD = (float*)alloc((size_t)BT*128*4);  // net ping      | sums hi
  float* bufA = (float*)alloc((size_t)BT*128*4);  // net pong / proj lo
  float* bufB = (float*)alloc((size_t)BT*128*4);  // pooled / proj hi
  float* cbuf = (float*)alloc((size_t)BT*128*4);  // c features
  float* sums = bufC;                              // spans bufC..bufD (67 MB, adjacent)
  if (off > ws_size) return;                       // workspace too small -> visible fail

  // bins live in the (not-yet-written) upper half of d_out: planes 3..5 region
  float* bins = out + (size_t)3*Bn*Hn*RRn;

  hipMemsetAsync(cnt, 0, (size_t)3*Bn*RRn*4, stream);
  k_idx  <<<BT/256, 256, 0, stream>>>(p, idx);
  k_count<<<(3*BT)/256, 256, 0, stream>>>(idx, cnt);

  for (int s = 0; s < 2; ++s) {
    const float* W0 = s ? cw0 : bw0;
    const float* B0 = s ? cb0 : bb0;
    const float* W1 = s ? cw1 : bw1;
    const float* B1 = s ? cb1 : bb1;
    const float* WS = s ? cws : bws;
    const float* FW = s ? fccw : fcw;
    const float* FB = s ? fccb : fcb;

    if (s) k_proj<true ><<<BT, 256, 0, stream>>>(p, p2, wp, bp, wp2, bp2, bufA, bufB);
    else   k_proj<false><<<BT, 256, 0, stream>>>(p, p2, wp, bp, wp2, bp2, bufA, bufB);

    // block 0: x = proj (bufA|bufB)
    k_gemm<2><<<BT/128, 256, 0, stream>>>(bufA, W0, bufB, W0 + 128*128,
                                          nullptr, nullptr, 0x3, B0, bufC);
    k_gemm<3><<<BT/128, 256, 0, stream>>>(bufC, W1, bufA, WS, bufB, WS + 128*128,
                                          0x1, B1, bufD);
    float* net = bufD; float* other = bufA;
    for (int blk = 1; blk < 5; ++blk) {
      k_reset  <<<(3*BT*32)/256, 256, 0, stream>>>(idx, bins);
      k_scatter<<<(3*BT*128)/256, 256, 0, stream>>>(idx, net, bins);
      k_gather <<<(BT*128)/256, 256, 0, stream>>>(idx, bins, bufB);
      const float* w0 = W0 + (size_t)blk*256*128;
      const float* w1 = W1 + (size_t)blk*128*128;
      const float* wS = WS + (size_t)blk*256*128;
      k_gemm<2><<<BT/128, 256, 0, stream>>>(net, w0, bufB, w0 + 128*128,
                                            nullptr, nullptr, 0x3, B0 + blk*128, bufC);
      k_gemm<3><<<BT/128, 256, 0, stream>>>(bufC, w1, net, wS, bufB, wS + 128*128,
                                            0x1, B1 + blk*128, other);
      float* t = net; net = other; other = t;
    }
    // final fc -> c features
    k_gemm<1><<<BT/128, 256, 0, stream>>>(net, FW, nullptr, nullptr, nullptr, nullptr,
                                          0x0, FB, cbuf);
    // scatter-mean into the 3 output planes of this stream
    for (int pl = 0; pl < 3; ++pl) {
      hipMemsetAsync(sums, 0, (size_t)Bn*RRn*128*4, stream);
      k_scatter_add<<<(BT*128)/256, 256, 0, stream>>>(idx + (size_t)pl*BT, cbuf, sums);
      k_finalize<<<((size_t)Bn*128*RRn)/256, 256, 0, stream>>>(
          sums, cnt + (size_t)pl*Bn*RRn, out + (size_t)(s*3+pl)*Bn*Hn*RRn);
    }
  }
}

// Round 2
// 2475.808 us; speedup vs baseline: 1.4621x; 1.4621x over previous
//
#include <hip/hip_runtime.h>
#include <cstdint>
#include <cstddef>

#define Bn 8
#define Tn 8192
#define BT (Bn*Tn)      // 65536 points
#define Hn 128
#define RRn 16384       // 128*128 bins per plane per batch

typedef unsigned short u16;
typedef __attribute__((ext_vector_type(8))) short s8v;   // 8 bf16 (4 VGPRs)
typedef __attribute__((ext_vector_type(4))) float f4v;   // 4 f32 acc

__device__ __forceinline__ u16 f2bf(float f) {
  unsigned u = __float_as_uint(f);
  unsigned r = (u + 0x7FFF + ((u >> 16) & 1)) >> 16;   // RNE
  return (u16)r;
}
__device__ __forceinline__ unsigned pack2(float a, float b) {
  return (unsigned)f2bf(a) | ((unsigned)f2bf(b) << 16);
}

// ---------------- index computation ----------------
__global__ void k_idx(const float* __restrict__ p, int* __restrict__ idx) {
  int i = blockIdx.x*256 + threadIdx.x;
  if (i >= BT) return;
  float v0 = p[i*3+0], v1 = p[i*3+1], v2 = p[i*3+2];
  float v[3] = {v0, v1, v2};
  const int A0[3] = {0,0,1};
  const int A1[3] = {2,1,2};
#pragma unroll
  for (int pl = 0; pl < 3; ++pl) {
    float a = v[A0[pl]] / 1.001f + 0.5f;
    float b = v[A1[pl]] / 1.001f + 0.5f;
    a = fminf(fmaxf(a, 0.0f), 0.999f);
    b = fminf(fmaxf(b, 0.0f), 0.999f);
    int ga = (int)floorf(a * 128.0f);
    int gb = (int)floorf(b * 128.0f);
    idx[pl*BT + i] = ga + 128*gb;
  }
}

__global__ void k_count(const int* __restrict__ idx, float* __restrict__ cnt) {
  int g = blockIdx.x*256 + threadIdx.x;
  if (g >= 3*BT) return;
  int pl = g / BT, i = g % BT;
  int b = i / Tn;
  int bin = idx[g];
  atomicAdd(&cnt[(pl*Bn + b)*RRn + bin], 1.0f);
}

// ---------------- weight prep: f32 [k][n] -> bf16 [n][k], 52 chunks of 128x128 ----
__global__ void k_prep(const float* __restrict__ bw0, const float* __restrict__ bw1,
                       const float* __restrict__ bws, const float* __restrict__ cw0,
                       const float* __restrict__ cw1, const float* __restrict__ cws,
                       const float* __restrict__ fcw, const float* __restrict__ fccw,
                       u16* __restrict__ arena) {
  int c = blockIdx.x;            // 0..51
  int s = c / 26, r = c % 26;
  const float* base;
  if (r < 10)      base = (s ? cw0 : bw0) + (size_t)(r >> 1)*32768 + (size_t)(r & 1)*16384;
  else if (r < 15) base = (s ? cw1 : bw1) + (size_t)(r - 10)*16384;
  else if (r < 25) base = (s ? cws : bws) + (size_t)((r - 15) >> 1)*32768 + (size_t)((r - 15) & 1)*16384;
  else             base = s ? fccw : fcw;
  __shared__ u16 ld[128*130];
#pragma unroll 4
  for (int it = 0; it < 64; ++it) {
    int lin = it*256 + threadIdx.x;
    int k = lin >> 7, n = lin & 127;
    ld[k*130 + n] = f2bf(base[lin]);
  }
  __syncthreads();
  u16* dst = arena + (size_t)c*16384;
#pragma unroll 4
  for (int it = 0; it < 64; ++it) {
    int lin = it*256 + threadIdx.x;
    int n = lin >> 7, k = lin & 127;
    dst[lin] = ld[k*130 + n];
  }
}

// ---------------- input projection ----------------
template<bool CORR>
__global__ void k_proj(const float* __restrict__ p, const float* __restrict__ p2,
                       const float* __restrict__ wp, const float* __restrict__ bp,
                       const float* __restrict__ wp2, const float* __restrict__ bp2,
                       float* __restrict__ outLo, float* __restrict__ outHi) {
  int t = blockIdx.x;
  int c = threadIdx.x;
  float a0 = p[t*3+0], a1 = p[t*3+1], a2 = p[t*3+2];
  float v = a0*wp[c] + a1*wp[256+c] + a2*wp[512+c] + bp[c];
  if (CORR) {
    float q0 = p2[t*3+0], q1 = p2[t*3+1], q2 = p2[t*3+2];
    v += q0*wp2[c] + q1*wp2[256+c] + q2*wp2[512+c] + bp2[c];
  }
  if (c < 128) outLo[(size_t)t*128 + c] = v;
  else         outHi[(size_t)t*128 + (c-128)] = v;
}

// ---------------- MFMA GEMM ----------------
// out[m][0:128] = bias + sum_s (relu_s? relu(x_s) : x_s)[m][0:128] @ W_s,  W_s given
// as bf16 [n][k] chunks. Tile: 128 rows x 128 cols, 256 thr = 4 waves, BK=64.
template<int NSEG>
__global__ __launch_bounds__(256) void k_gemm(
    const float* __restrict__ x0g, const u16* __restrict__ w0g,
    const float* __restrict__ x1g, const u16* __restrict__ w1g,
    const float* __restrict__ x2g, const u16* __restrict__ w2g,
    int reluMask, const float* __restrict__ bias, float* __restrict__ outp)
{
  __shared__ u16 As[128*72];   // [row][k] pad 72 (144 B rows -> balanced banks)
  __shared__ u16 Bs[128*72];   // [n][k]
  const int tid = threadIdx.x;
  const size_t row0 = (size_t)blockIdx.x * 128;

  f4v acc[2][8];
#pragma unroll
  for (int i = 0; i < 2; ++i)
#pragma unroll
    for (int j = 0; j < 8; ++j) acc[i][j] = (f4v){0.f, 0.f, 0.f, 0.f};

  const float* Xg[3] = {x0g, x1g, x2g};
  const u16*   Wg[3] = {w0g, w1g, w2g};

  const int trow = tid >> 1, th = tid & 1;
  const int l = tid & 63, w = tid >> 6;
  const int lm = l & 15, lg = l >> 4;
  const u16* pa = As + (w*32 + lm)*72 + lg*8;
  const u16* pb = Bs + lm*72 + lg*8;

#pragma unroll
  for (int s = 0; s < NSEG; ++s) {
    const float* __restrict__ X = Xg[s];
    const u16*   __restrict__ W = Wg[s];
    const bool rel = (reluMask >> s) & 1;
#pragma unroll 1
    for (int half = 0; half < 2; ++half) {
      const int k0 = half * 64;
      __syncthreads();
      {
        const float* xrow = X + (row0 + trow)*128 + k0 + th*32;
        u16* la = As + trow*72 + th*32;
#pragma unroll
        for (int u = 0; u < 4; ++u) {
          float4 v0 = *reinterpret_cast<const float4*>(xrow + u*8);
          float4 v1 = *reinterpret_cast<const float4*>(xrow + u*8 + 4);
          if (rel) {
            v0.x = fmaxf(v0.x, 0.f); v0.y = fmaxf(v0.y, 0.f);
            v0.z = fmaxf(v0.z, 0.f); v0.w = fmaxf(v0.w, 0.f);
            v1.x = fmaxf(v1.x, 0.f); v1.y = fmaxf(v1.y, 0.f);
            v1.z = fmaxf(v1.z, 0.f); v1.w = fmaxf(v1.w, 0.f);
          }
          uint4 o;
          o.x = pack2(v0.x, v0.y); o.y = pack2(v0.z, v0.w);
          o.z = pack2(v1.x, v1.y); o.w = pack2(v1.z, v1.w);
          *reinterpret_cast<uint4*>(la + u*8) = o;
        }
        const u16* wrow = W + trow*128 + k0 + th*32;
        u16* lb = Bs + trow*72 + th*32;
#pragma unroll
        for (int u = 0; u < 4; ++u)
          *reinterpret_cast<uint4*>(lb + u*8) =
              *reinterpret_cast<const uint4*>(wrow + u*8);
      }
      __syncthreads();
#pragma unroll
      for (int kk = 0; kk < 2; ++kk) {
        s8v a0 = *reinterpret_cast<const s8v*>(pa + kk*32);
        s8v a1 = *reinterpret_cast<const s8v*>(pa + 16*72 + kk*32);
        s8v b[8];
#pragma unroll
        for (int nj = 0; nj < 8; ++nj)
          b[nj] = *reinterpret_cast<const s8v*>(pb + nj*16*72 + kk*32);
#pragma unroll
        for (int nj = 0; nj < 8; ++nj) {
          acc[0][nj] = __builtin_amdgcn_mfma_f32_16x16x32_bf16(a0, b[nj], acc[0][nj], 0, 0, 0);
          acc[1][nj] = __builtin_amdgcn_mfma_f32_16x16x32_bf16(a1, b[nj], acc[1][nj], 0, 0, 0);
        }
      }
    }
  }
  // epilogue: C/D layout col=lane&15, row=(lane>>4)*4+reg
#pragma unroll
  for (int nj = 0; nj < 8; ++nj) {
    const int col = nj*16 + lm;
    const float bv = bias[col];
#pragma unroll
    for (int mi = 0; mi < 2; ++mi) {
      const size_t rb = row0 + w*32 + mi*16 + lg*4;
#pragma unroll
      for (int r = 0; r < 4; ++r)
        outp[(rb + r)*128 + col] = acc[mi][nj][r] + bv;
    }
  }
}

// ---------------- pooling ----------------
__device__ __forceinline__ void atomicMaxF(float* addr, float val) {
  unsigned int bits = __float_as_uint(val);
  if (!(bits >> 31)) atomicMax((int*)addr, (int)bits);
  else               atomicMin((unsigned int*)addr, bits);
}

__global__ void k_reset(const int* __restrict__ idx, float* __restrict__ bins) {
  int g = blockIdx.x*256 + threadIdx.x;   // 3*BT*32
  int c4 = g & 31;
  int r = g >> 5;
  if (r >= 3*BT) return;
  int pl = r / BT, i = r % BT;
  int b = i / Tn;
  int bin = idx[pl*BT + i];
  const float ninf = -__builtin_inff();
  float4 v = make_float4(ninf, ninf, ninf, ninf);
  *reinterpret_cast<float4*>(&bins[((size_t)(pl*Bn + b)*RRn + bin)*128 + c4*4]) = v;
}

__global__ void k_scatter(const int* __restrict__ idx, const float* __restrict__ net,
                          float* __restrict__ bins) {
  int g = blockIdx.x*256 + threadIdx.x;   // 3*BT*128
  int chn = g & 127;
  int r = g >> 7;
  if (r >= 3*BT) return;
  int pl = r / BT, i = r % BT;
  int b = i / Tn;
  int bin = idx[pl*BT + i];
  float v = net[(size_t)i*128 + chn];
  atomicMaxF(&bins[((size_t)(pl*Bn + b)*RRn + bin)*128 + chn], v);
}

__global__ void k_gather(const int* __restrict__ idx, const float* __restrict__ bins,
                         float* __restrict__ pooled) {
  int g = blockIdx.x*256 + threadIdx.x;   // BT*128
  int chn = g & 127;
  int i = g >> 7;
  if (i >= BT) return;
  int b = i / Tn;
  float s = 0.0f;
#pragma unroll
  for (int pl = 0; pl < 3; ++pl) {
    int bin = idx[pl*BT + i];
    float v = bins[((size_t)(pl*Bn + b)*RRn + bin)*128 + chn];
    if (!isinf(v)) s += v;
  }
  pooled[(size_t)i*128 + chn] = s;
}

// ---------------- scatter-mean output ----------------
__global__ void k_zero_sums(const int* __restrict__ idxp, float* __restrict__ sums) {
  int g = blockIdx.x*256 + threadIdx.x;   // BT*32
  int c4 = g & 31;
  int i = g >> 5;
  if (i >= BT) return;
  int b = i >> 13;
  int bin = idxp[i];
  *reinterpret_cast<float4*>(&sums[((size_t)b*RRn + bin)*128 + c4*4]) =
      make_float4(0.f, 0.f, 0.f, 0.f);
}

__global__ void k_scatter_add(const int* __restrict__ idxp, const float* __restrict__ c,
                              float* __restrict__ sums) {
  int g = blockIdx.x*256 + threadIdx.x;   // BT*128
  int chn = g & 127;
  int i = g >> 7;
  if (i >= BT) return;
  int b = i >> 13;
  int bin = idxp[i];
  atomicAdd(&sums[((size_t)b*RRn + bin)*128 + chn], c[(size_t)i*128 + chn]);
}

__global__ void k_finalize(const float* __restrict__ sums, const float* __restrict__ cnt,
                           float* __restrict__ outp) {
  int g = blockIdx.x*256 + threadIdx.x;   // Bn*128*RRn
  int bin = g & (RRn - 1);
  int chn = (g >> 14) & 127;
  int b = g >> 21;
  if (b >= Bn) return;
  float n = cnt[b*RRn + bin];
  float r = 0.f;
  if (n > 0.f) r = sums[((size_t)b*RRn + bin)*128 + chn] / n;
  outp[((size_t)b*128 + chn)*RRn + bin] = r;
}

// ---------------- host ----------------
extern "C" void kernel_launch(void* const* d_in, const int* in_sizes, int n_in,
                              void* d_out_v, int out_size, void* d_ws, size_t ws_size,
                              hipStream_t stream) {
  const float* p    = (const float*)d_in[0];
  const float* p2   = (const float*)d_in[1];
  const float* wp   = (const float*)d_in[2];
  const float* bp   = (const float*)d_in[3];
  const float* wp2  = (const float*)d_in[4];
  const float* bp2  = (const float*)d_in[5];
  const float* bw0  = (const float*)d_in[6];
  const float* bb0  = (const float*)d_in[7];
  const float* bw1  = (const float*)d_in[8];
  const float* bb1  = (const float*)d_in[9];
  const float* bws  = (const float*)d_in[10];
  const float* cw0  = (const float*)d_in[11];
  const float* cb0  = (const float*)d_in[12];
  const float* cw1  = (const float*)d_in[13];
  const float* cb1  = (const float*)d_in[14];
  const float* cws  = (const float*)d_in[15];
  const float* fcw  = (const float*)d_in[16];
  const float* fcb  = (const float*)d_in[17];
  const float* fccw = (const float*)d_in[18];
  const float* fccb = (const float*)d_in[19];
  float* out = (float*)d_out_v;

  size_t off = 0;
  auto alloc = [&](size_t bytes) -> char* {
    char* r = (char*)d_ws + off;
    off += (bytes + 255) & ~(size_t)255;
    return r;
  };
  int*   idx   = (int*)  alloc((size_t)3*BT*4);
  float* cnt   = (float*)alloc((size_t)3*Bn*RRn*4);
  u16*   arena = (u16*)  alloc((size_t)52*16384*2);
  float* bufC  = (float*)alloc((size_t)BT*128*4);
  float* bufD  = (float*)alloc((size_t)BT*128*4);
  float* bufA  = (float*)alloc((size_t)BT*128*4);
  float* bufB  = (float*)alloc((size_t)BT*128*4);
  float* cbuf  = (float*)alloc((size_t)BT*128*4);
  float* sums  = bufC;                         // spans bufC..bufD (67 MB adjacent)
  if (off > ws_size) return;

  float* bins = out + (size_t)3*Bn*Hn*RRn;     // dead upper half of d_out until final phase

  hipMemsetAsync(cnt, 0, (size_t)3*Bn*RRn*4, stream);
  k_prep <<<52, 256, 0, stream>>>(bw0, bw1, bws, cw0, cw1, cws, fcw, fccw, arena);
  k_idx  <<<BT/256, 256, 0, stream>>>(p, idx);
  k_count<<<(3*BT)/256, 256, 0, stream>>>(idx, cnt);

  for (int s = 0; s < 2; ++s) {
    const float* B0 = s ? cb0 : bb0;
    const float* B1 = s ? cb1 : bb1;
    const float* FB = s ? fccb : fcb;
    auto WT = [&](int chunk) -> const u16* {
      return arena + (size_t)(s*26 + chunk)*16384;
    };

    if (s) k_proj<true ><<<BT, 256, 0, stream>>>(p, p2, wp, bp, wp2, bp2, bufA, bufB);
    else   k_proj<false><<<BT, 256, 0, stream>>>(p, p2, wp, bp, wp2, bp2, bufA, bufB);

    // block 0
    k_gemm<2><<<BT/128, 256, 0, stream>>>(bufA, WT(0), bufB, WT(1),
                                          nullptr, nullptr, 0x3, B0, bufC);
    k_gemm<3><<<BT/128, 256, 0, stream>>>(bufC, WT(10), bufA, WT(15), bufB, WT(16),
                                          0x1, B1, bufD);
    float* net = bufD; float* other = bufA;
    for (int blk = 1; blk < 5; ++blk) {
      k_reset  <<<(3*BT*32)/256, 256, 0, stream>>>(idx, bins);
      k_scatter<<<(3*BT*128)/256, 256, 0, stream>>>(idx, net, bins);
      k_gather <<<(BT*128)/256, 256, 0, stream>>>(idx, bins, bufB);
      k_gemm<2><<<BT/128, 256, 0, stream>>>(net, WT(2*blk), bufB, WT(2*blk+1),
                                            nullptr, nullptr, 0x3, B0 + blk*128, bufC);
      k_gemm<3><<<BT/128, 256, 0, stream>>>(bufC, WT(10+blk), net, WT(15+2*blk),
                                            bufB, WT(16+2*blk), 0x1, B1 + blk*128, other);
      float* t = net; net = other; other = t;
    }
    k_gemm<1><<<BT/128, 256, 0, stream>>>(net, WT(25), nullptr, nullptr,
                                          nullptr, nullptr, 0x0, FB, cbuf);

    for (int pl = 0; pl < 3; ++pl) {
      k_zero_sums  <<<(BT*32)/256, 256, 0, stream>>>(idx + (size_t)pl*BT, sums);
      k_scatter_add<<<(BT*128)/256, 256, 0, stream>>>(idx + (size_t)pl*BT, cbuf, sums);
      k_finalize<<<((size_t)Bn*128*RRn)/256, 256, 0, stream>>>(
          sums, cnt + (size_t)pl*Bn*RRn, out + (size_t)(s*3+pl)*Bn*Hn*RRn);
    }
  }
}

// Round 3
// 918.641 us; speedup vs baseline: 3.9404x; 2.6951x over previous
//
#include <hip/hip_runtime.h>
#include <cstdint>
#include <cstddef>

#define Bn 8
#define Tn 8192
#define BT (Bn*Tn)      // 65536 points
#define Hn 128
#define RRn 16384       // 128*128 bins per plane per batch

typedef unsigned short u16;
typedef __attribute__((ext_vector_type(8))) short s8v;   // 8 bf16 (4 VGPRs)
typedef __attribute__((ext_vector_type(4))) float f4v;   // 4 f32 acc

__device__ __forceinline__ u16 f2bf(float f) {
  unsigned u = __float_as_uint(f);
  unsigned r = (u + 0x7FFF + ((u >> 16) & 1)) >> 16;   // RNE
  return (u16)r;
}

__device__ __forceinline__ s8v relu8(s8v a) {
  union { s8v s; unsigned u[4]; } x; x.s = a;
#pragma unroll
  for (int k = 0; k < 4; ++k) {
    unsigned m = ((x.u[k] & 0x80008000u) >> 15) * 0xFFFFu;
    x.u[k] &= ~m;
  }
  return x.s;
}

__device__ __forceinline__ void upk(unsigned u, float& lo, float& hi) {
  lo = __uint_as_float(u << 16);
  hi = __uint_as_float(u & 0xFFFF0000u);
}

// ---------------- index computation ----------------
__global__ void k_idx(const float* __restrict__ p, int* __restrict__ idx) {
  int i = blockIdx.x*256 + threadIdx.x;
  if (i >= BT) return;
  float v0 = p[i*3+0], v1 = p[i*3+1], v2 = p[i*3+2];
  float v[3] = {v0, v1, v2};
  const int A0[3] = {0,0,1};
  const int A1[3] = {2,1,2};
#pragma unroll
  for (int pl = 0; pl < 3; ++pl) {
    float a = v[A0[pl]] / 1.001f + 0.5f;
    float b = v[A1[pl]] / 1.001f + 0.5f;
    a = fminf(fmaxf(a, 0.0f), 0.999f);
    b = fminf(fmaxf(b, 0.0f), 0.999f);
    int ga = (int)floorf(a * 128.0f);
    int gb = (int)floorf(b * 128.0f);
    idx[pl*BT + i] = ga + 128*gb;
  }
}

// ---------------- CSR build (idx is static across all pooling rounds) ----------------
__global__ void k_hist(const int* __restrict__ idx, int* __restrict__ cnt32) {
  int g = blockIdx.x*256 + threadIdx.x;
  if (g >= 3*BT) return;
  int pl = g >> 16, i = g & (BT-1);
  int b = i >> 13;
  atomicAdd(&cnt32[(pl*Bn + b)*RRn + idx[g]], 1);
}

__global__ void k_scan(const int* __restrict__ cnt32, int* __restrict__ starts,
                       int* __restrict__ cursor) {
  int seg = blockIdx.x;                 // 0..23
  const int* c = cnt32 + seg*RRn;
  int* st = starts + seg*RRn;
  int* cu = cursor + seg*RRn;
  int t = threadIdx.x;                  // 256 threads, 64 bins each
  __shared__ int part[256];
  int base = t*64;
  int sum = 0;
#pragma unroll 8
  for (int j = 0; j < 64; ++j) sum += c[base+j];
  part[t] = sum; __syncthreads();
  for (int ofs = 1; ofs < 256; ofs <<= 1) {
    int v = (t >= ofs) ? part[t-ofs] : 0;
    __syncthreads();
    part[t] += v;
    __syncthreads();
  }
  int run = (t ? part[t-1] : 0) + seg*Tn;
#pragma unroll 8
  for (int j = 0; j < 64; ++j) { st[base+j] = run; cu[base+j] = run; run += c[base+j]; }
}

__global__ void k_fill(const int* __restrict__ idx, int* __restrict__ cursor,
                       int* __restrict__ sorted) {
  int g = blockIdx.x*256 + threadIdx.x;
  if (g >= 3*BT) return;
  int pl = g >> 16, i = g & (BT-1);
  int b = i >> 13;
  int pos = atomicAdd(&cursor[(pl*Bn + b)*RRn + idx[g]], 1);
  sorted[pos] = i;
}

// ---------------- weight prep: f32 [k][n] -> bf16 [n][k], 52 chunks of 128x128 ----
__global__ void k_prep(const float* __restrict__ bw0, const float* __restrict__ bw1,
                       const float* __restrict__ bws, const float* __restrict__ cw0,
                       const float* __restrict__ cw1, const float* __restrict__ cws,
                       const float* __restrict__ fcw, const float* __restrict__ fccw,
                       u16* __restrict__ arena) {
  int c = blockIdx.x;            // 0..51
  int s = c / 26, r = c % 26;
  const float* base;
  if (r < 10)      base = (s ? cw0 : bw0) + (size_t)(r >> 1)*32768 + (size_t)(r & 1)*16384;
  else if (r < 15) base = (s ? cw1 : bw1) + (size_t)(r - 10)*16384;
  else if (r < 25) base = (s ? cws : bws) + (size_t)((r - 15) >> 1)*32768 + (size_t)((r - 15) & 1)*16384;
  else             base = s ? fccw : fcw;
  __shared__ u16 ld[128*130];
#pragma unroll 4
  for (int it = 0; it < 64; ++it) {
    int lin = it*256 + threadIdx.x;
    int k = lin >> 7, n = lin & 127;
    ld[k*130 + n] = f2bf(base[lin]);
  }
  __syncthreads();
  u16* dst = arena + (size_t)c*16384;
#pragma unroll 4
  for (int it = 0; it < 64; ++it) {
    int lin = it*256 + threadIdx.x;
    int n = lin >> 7, k = lin & 127;
    dst[lin] = ld[k*130 + n];
  }
}

// ---------------- input projection (bf16 out) ----------------
template<bool CORR>
__global__ void k_proj(const float* __restrict__ p, const float* __restrict__ p2,
                       const float* __restrict__ wp, const float* __restrict__ bp,
                       const float* __restrict__ wp2, const float* __restrict__ bp2,
                       u16* __restrict__ outLo, u16* __restrict__ outHi) {
  int t = blockIdx.x;
  int c = threadIdx.x;
  float a0 = p[t*3+0], a1 = p[t*3+1], a2 = p[t*3+2];
  float v = a0*wp[c] + a1*wp[256+c] + a2*wp[512+c] + bp[c];
  if (CORR) {
    float q0 = p2[t*3+0], q1 = p2[t*3+1], q2 = p2[t*3+2];
    v += q0*wp2[c] + q1*wp2[256+c] + q2*wp2[512+c] + bp2[c];
  }
  u16 r = f2bf(v);
  if (c < 128) outLo[(size_t)t*128 + c] = r;
  else         outHi[(size_t)t*128 + (c-128)] = r;
}

// ---------------- fused ResNet block ----------------
// x = [xA | xB] (each [BT][128] bf16), K=256.
// hidden = relu( relu(x) @ w0 + b0 )       (in LDS, never global)
// out    = x @ ws + hidden @ w1 + b1       (bf16)
// FC: cout = out @ fcw + fcb  (out never written to global)
template<bool FC>
__global__ __launch_bounds__(512) void k_rb(
    const u16* __restrict__ xA, const u16* __restrict__ xB,
    const u16* __restrict__ w00, const u16* __restrict__ w01,
    const u16* __restrict__ ws0, const u16* __restrict__ ws1,
    const u16* __restrict__ w1c,
    const float* __restrict__ b0, const float* __restrict__ b1,
    const u16* __restrict__ fcw, const float* __restrict__ fcb,
    u16* __restrict__ outp)
{
  __shared__ u16 xs [128*72];
  __shared__ u16 w0s[128*72];
  __shared__ u16 wss[128*72];
  __shared__ u16 hid[128*136];
  const int tid = threadIdx.x;
  const size_t row0 = (size_t)blockIdx.x * 128;
  const int l = tid & 63, w = tid >> 6;     // 8 waves, 16 rows each
  const int lm = l & 15, lg = l >> 4;
  const int trow = tid >> 2, tq = tid & 3;  // staging: 32B per thread per buffer

  f4v acc_h[8], acc_s[8];
#pragma unroll
  for (int j = 0; j < 8; ++j) { acc_h[j] = (f4v){0,0,0,0}; acc_s[j] = (f4v){0,0,0,0}; }

  const u16* pa  = xs  + (w*16 + lm)*72 + lg*8;
  const u16* pbh = w0s + lm*72 + lg*8;
  const u16* pbs = wss + lm*72 + lg*8;

#pragma unroll 1
  for (int kc = 0; kc < 4; ++kc) {
    const u16* xsrc  = (kc < 2) ? xA  : xB;
    const u16* w0src = (kc < 2) ? w00 : w01;
    const u16* wssrc = (kc < 2) ? ws0 : ws1;
    const int k0 = (kc & 1) * 64;
    __syncthreads();
    {
      const u16* s1 = xsrc + (row0 + trow)*128 + k0 + tq*16;
      uint4* d1 = (uint4*)(xs + trow*72 + tq*16);
      d1[0] = ((const uint4*)s1)[0]; d1[1] = ((const uint4*)s1)[1];
      const u16* s2 = w0src + trow*128 + k0 + tq*16;
      uint4* d2 = (uint4*)(w0s + trow*72 + tq*16);
      d2[0] = ((const uint4*)s2)[0]; d2[1] = ((const uint4*)s2)[1];
      const u16* s3 = wssrc + trow*128 + k0 + tq*16;
      uint4* d3 = (uint4*)(wss + trow*72 + tq*16);
      d3[0] = ((const uint4*)s3)[0]; d3[1] = ((const uint4*)s3)[1];
    }
    __syncthreads();
#pragma unroll
    for (int kk = 0; kk < 2; ++kk) {
      s8v a  = *(const s8v*)(pa + kk*32);
      s8v ar = relu8(a);
#pragma unroll
      for (int nj = 0; nj < 8; ++nj) {
        s8v bh = *(const s8v*)(pbh + nj*16*72 + kk*32);
        acc_h[nj] = __builtin_amdgcn_mfma_f32_16x16x32_bf16(ar, bh, acc_h[nj], 0, 0, 0);
      }
#pragma unroll
      for (int nj = 0; nj < 8; ++nj) {
        s8v bs = *(const s8v*)(pbs + nj*16*72 + kk*32);
        acc_s[nj] = __builtin_amdgcn_mfma_f32_16x16x32_bf16(a, bs, acc_s[nj], 0, 0, 0);
      }
    }
  }
  __syncthreads();   // all pass-1 MFMA reads done
  // stage w1 halves; write hidden = relu(acc_h + b0)
  {
    const u16* s1 = w1c + trow*128 + tq*16;
    uint4* d1 = (uint4*)(w0s + trow*72 + tq*16);
    d1[0] = ((const uint4*)s1)[0]; d1[1] = ((const uint4*)s1)[1];
    const u16* s2 = w1c + trow*128 + 64 + tq*16;
    uint4* d2 = (uint4*)(wss + trow*72 + tq*16);
    d2[0] = ((const uint4*)s2)[0]; d2[1] = ((const uint4*)s2)[1];
#pragma unroll
    for (int nj = 0; nj < 8; ++nj) {
      const int col = nj*16 + lm;
      const float bv = b0[col];
#pragma unroll
      for (int r = 0; r < 4; ++r) {
        int row = w*16 + lg*4 + r;
        hid[row*136 + col] = f2bf(fmaxf(acc_h[nj][r] + bv, 0.0f));
      }
    }
  }
  __syncthreads();
  // pass 2: acc_s += hidden @ w1
  {
    const u16* pah = hid + (w*16 + lm)*136 + lg*8;
#pragma unroll
    for (int kk = 0; kk < 4; ++kk) {
      s8v a = *(const s8v*)(pah + kk*32);
      const u16* pb = ((kk < 2) ? w0s : wss) + lm*72 + lg*8 + (kk & 1)*32;
#pragma unroll
      for (int nj = 0; nj < 8; ++nj) {
        s8v bb = *(const s8v*)(pb + nj*16*72);
        acc_s[nj] = __builtin_amdgcn_mfma_f32_16x16x32_bf16(a, bb, acc_s[nj], 0, 0, 0);
      }
    }
  }
  if (!FC) {
#pragma unroll
    for (int nj = 0; nj < 8; ++nj) {
      const int col = nj*16 + lm;
      const float bv = b1[col];
#pragma unroll
      for (int r = 0; r < 4; ++r) {
        int row = w*16 + lg*4 + r;
        outp[(row0 + row)*128 + col] = f2bf(acc_s[nj][r] + bv);
      }
    }
  } else {
    __syncthreads();   // pass-2 reads of hid/w0s/wss done
#pragma unroll
    for (int nj = 0; nj < 8; ++nj) {
      const int col = nj*16 + lm;
      const float bv = b1[col];
#pragma unroll
      for (int r = 0; r < 4; ++r) {
        int row = w*16 + lg*4 + r;
        hid[row*136 + col] = f2bf(acc_s[nj][r] + bv);
      }
    }
    const u16* s1 = fcw + trow*128 + tq*16;
    uint4* d1 = (uint4*)(w0s + trow*72 + tq*16);
    d1[0] = ((const uint4*)s1)[0]; d1[1] = ((const uint4*)s1)[1];
    const u16* s2 = fcw + trow*128 + 64 + tq*16;
    uint4* d2 = (uint4*)(wss + trow*72 + tq*16);
    d2[0] = ((const uint4*)s2)[0]; d2[1] = ((const uint4*)s2)[1];
    __syncthreads();
    f4v accf[8];
#pragma unroll
    for (int j = 0; j < 8; ++j) accf[j] = (f4v){0,0,0,0};
    const u16* pah = hid + (w*16 + lm)*136 + lg*8;
#pragma unroll
    for (int kk = 0; kk < 4; ++kk) {
      s8v a = *(const s8v*)(pah + kk*32);
      const u16* pb = ((kk < 2) ? w0s : wss) + lm*72 + lg*8 + (kk & 1)*32;
#pragma unroll
      for (int nj = 0; nj < 8; ++nj) {
        s8v bb = *(const s8v*)(pb + nj*16*72);
        accf[nj] = __builtin_amdgcn_mfma_f32_16x16x32_bf16(a, bb, accf[nj], 0, 0, 0);
      }
    }
#pragma unroll
    for (int nj = 0; nj < 8; ++nj) {
      const int col = nj*16 + lm;
      const float bv = fcb[col];
#pragma unroll
      for (int r = 0; r < 4; ++r) {
        int row = w*16 + lg*4 + r;
        outp[(row0 + row)*128 + col] = f2bf(accf[nj][r] + bv);
      }
    }
  }
}

// ---------------- CSR pooling: pooled[i] = sum_pl max_{j in bin(i,pl)} net[j] ----
__global__ void k_pool(const int* __restrict__ idx, const int* __restrict__ starts,
                       const int* __restrict__ cnt32, const int* __restrict__ sorted,
                       const u16* __restrict__ net, u16* __restrict__ pooled) {
  int g = blockIdx.x*256 + threadIdx.x;    // BT*16
  int sl = g & 15;
  int i = g >> 4;
  if (i >= BT) return;
  int b = i >> 13;
  float acc[8];
#pragma unroll
  for (int k = 0; k < 8; ++k) acc[k] = 0.0f;
#pragma unroll
  for (int pl = 0; pl < 3; ++pl) {
    int seg = (pl*Bn + b)*RRn + idx[pl*BT + i];
    int s = starts[seg];
    int e = s + cnt32[seg];
    float mx[8];
#pragma unroll
    for (int k = 0; k < 8; ++k) mx[k] = -3.0e38f;
    for (int j = s; j < e; ++j) {
      int jj = sorted[j];
      uint4 v = *(const uint4*)(net + (size_t)jj*128 + sl*8);
      float lo, hi;
      upk(v.x, lo, hi); mx[0] = fmaxf(mx[0], lo); mx[1] = fmaxf(mx[1], hi);
      upk(v.y, lo, hi); mx[2] = fmaxf(mx[2], lo); mx[3] = fmaxf(mx[3], hi);
      upk(v.z, lo, hi); mx[4] = fmaxf(mx[4], lo); mx[5] = fmaxf(mx[5], hi);
      upk(v.w, lo, hi); mx[6] = fmaxf(mx[6], lo); mx[7] = fmaxf(mx[7], hi);
    }
#pragma unroll
    for (int k = 0; k < 8; ++k) acc[k] += mx[k];
  }
  union { uint4 v; unsigned u[4]; } o;
#pragma unroll
  for (int k = 0; k < 4; ++k)
    o.u[k] = (unsigned)f2bf(acc[2*k]) | ((unsigned)f2bf(acc[2*k+1]) << 16);
  *(uint4*)(pooled + (size_t)i*128 + sl*8) = o.v;
}

// ---------------- CSR scatter-mean into output planes ----------------
__global__ void k_mean(const int* __restrict__ starts, const int* __restrict__ cnt32,
                       const int* __restrict__ sorted, const u16* __restrict__ cbuf,
                       float* __restrict__ out, int planeBase) {
  int g = blockIdx.x*256 + threadIdx.x;    // 3*Bn*RRn*16
  int sl = g & 15;
  int bin = (g >> 4) & (RRn - 1);
  int r = g >> 18;
  int b = r & 7, pl = r >> 3;
  if (pl >= 3) return;
  int seg = (pl*Bn + b)*RRn + bin;
  int c = cnt32[seg];
  if (c == 0) return;                      // out pre-zeroed
  int s = starts[seg];
  float sum[8];
#pragma unroll
  for (int k = 0; k < 8; ++k) sum[k] = 0.0f;
  for (int j = s; j < s + c; ++j) {
    int jj = sorted[j];
    uint4 v = *(const uint4*)(cbuf + (size_t)jj*128 + sl*8);
    float lo, hi;
    upk(v.x, lo, hi); sum[0] += lo; sum[1] += hi;
    upk(v.y, lo, hi); sum[2] += lo; sum[3] += hi;
    upk(v.z, lo, hi); sum[4] += lo; sum[5] += hi;
    upk(v.w, lo, hi); sum[6] += lo; sum[7] += hi;
  }
  float inv = 1.0f / (float)c;
  int plane = planeBase + pl;
  size_t base = ((size_t)(plane*Bn + b)*Hn + sl*8)*RRn + bin;
#pragma unroll
  for (int k = 0; k < 8; ++k)
    out[base + (size_t)k*RRn] = sum[k] * inv;
}

// ---------------- host ----------------
extern "C" void kernel_launch(void* const* d_in, const int* in_sizes, int n_in,
                              void* d_out_v, int out_size, void* d_ws, size_t ws_size,
                              hipStream_t stream) {
  const float* p    = (const float*)d_in[0];
  const float* p2   = (const float*)d_in[1];
  const float* wp   = (const float*)d_in[2];
  const float* bp   = (const float*)d_in[3];
  const float* wp2  = (const float*)d_in[4];
  const float* bp2  = (const float*)d_in[5];
  const float* bw0  = (const float*)d_in[6];
  const float* bb0  = (const float*)d_in[7];
  const float* bw1  = (const float*)d_in[8];
  const float* bb1  = (const float*)d_in[9];
  const float* bws  = (const float*)d_in[10];
  const float* cw0  = (const float*)d_in[11];
  const float* cb0  = (const float*)d_in[12];
  const float* cw1  = (const float*)d_in[13];
  const float* cb1  = (const float*)d_in[14];
  const float* cws  = (const float*)d_in[15];
  const float* fcw  = (const float*)d_in[16];
  const float* fcb  = (const float*)d_in[17];
  const float* fccw = (const float*)d_in[18];
  const float* fccb = (const float*)d_in[19];
  float* out = (float*)d_out_v;

  size_t off = 0;
  auto alloc = [&](size_t bytes) -> char* {
    char* r = (char*)d_ws + off;
    off += (bytes + 255) & ~(size_t)255;
    return r;
  };
  int* idx    = (int*)alloc((size_t)3*BT*4);
  int* cnt32  = (int*)alloc((size_t)3*Bn*RRn*4);
  int* starts = (int*)alloc((size_t)3*Bn*RRn*4);
  int* cursor = (int*)alloc((size_t)3*Bn*RRn*4);
  int* sorted = (int*)alloc((size_t)3*BT*4);
  u16* arena  = (u16*)alloc((size_t)52*16384*2);
  u16* buf0   = (u16*)alloc((size_t)BT*128*2);
  u16* buf1   = (u16*)alloc((size_t)BT*128*2);
  u16* bufP   = (u16*)alloc((size_t)BT*128*2);
  u16* cbuf   = (u16*)alloc((size_t)BT*128*2);
  if (off > ws_size) return;

  hipMemsetAsync(out, 0, (size_t)out_size*4, stream);
  hipMemsetAsync(cnt32, 0, (size_t)3*Bn*RRn*4, stream);
  k_prep<<<52, 256, 0, stream>>>(bw0, bw1, bws, cw0, cw1, cws, fcw, fccw, arena);
  k_idx <<<BT/256, 256, 0, stream>>>(p, idx);
  k_hist<<<(3*BT)/256, 256, 0, stream>>>(idx, cnt32);
  k_scan<<<24, 256, 0, stream>>>(cnt32, starts, cursor);
  k_fill<<<(3*BT)/256, 256, 0, stream>>>(idx, cursor, sorted);

  for (int s = 0; s < 2; ++s) {
    const float* B0 = s ? cb0 : bb0;
    const float* B1 = s ? cb1 : bb1;
    const float* FB = s ? fccb : fcb;
    auto WT = [&](int chunk) -> const u16* {
      return arena + (size_t)(s*26 + chunk)*16384;
    };

    if (s) k_proj<true ><<<BT, 256, 0, stream>>>(p, p2, wp, bp, wp2, bp2, buf0, bufP);
    else   k_proj<false><<<BT, 256, 0, stream>>>(p, p2, wp, bp, wp2, bp2, buf0, bufP);

    // block 0
    k_rb<false><<<BT/128, 512, 0, stream>>>(buf0, bufP, WT(0), WT(1), WT(15), WT(16),
                                            WT(10), B0, B1, nullptr, nullptr, buf1);
    u16* net = buf1; u16* other = buf0;
    for (int blk = 1; blk < 4; ++blk) {
      k_pool<<<(BT*16)/256, 256, 0, stream>>>(idx, starts, cnt32, sorted, net, bufP);
      k_rb<false><<<BT/128, 512, 0, stream>>>(net, bufP, WT(2*blk), WT(2*blk+1),
                                              WT(15+2*blk), WT(16+2*blk), WT(10+blk),
                                              B0 + blk*128, B1 + blk*128,
                                              nullptr, nullptr, other);
      u16* t = net; net = other; other = t;
    }
    // block 4 fused with final fc -> cbuf
    k_pool<<<(BT*16)/256, 256, 0, stream>>>(idx, starts, cnt32, sorted, net, bufP);
    k_rb<true><<<BT/128, 512, 0, stream>>>(net, bufP, WT(8), WT(9), WT(23), WT(24),
                                           WT(14), B0 + 4*128, B1 + 4*128,
                                           WT(25), FB, cbuf);
    // scatter-mean all 3 planes of this stream
    k_mean<<<(3*Bn*RRn*16)/256, 256, 0, stream>>>(starts, cnt32, sorted, cbuf, out, s*3);
  }
}